// Round 19
// baseline (422.060 us; speedup 1.0000x reference)
//
#include <hip/hip_runtime.h>
#include <stdint.h>
#include <limits.h>

// StackMachineCell — LUT design (round 19).
// r18 null: global_load_lds->ds_read forces conservative vmcnt(0) each step
// (compiler can't prove non-aliasing) -> prefetch distance collapsed to ~1.
// This round: slice lives in REGISTERS (16 VGPR = 4x uint4 per step-buffer,
// 4 buffers, unroll-4 for static naming). Register loads are per-reg
// scoreboarded -> counted vmcnt waits are automatic; 3-position prefetch
// distance (~500cy) >= L2 latency -> waits free. Dependent access = 15
// v_cndmask uniform select tree (scalar bits) + v_readlane (~80cy).
// Decision bits / update rule / traj / phase2 / precompute byte-identical ->
// absmax must stay 0.0009765625.
// ws: Mm32@0 | Ms32@17408 | Mb32@50176 | MmT@115712 | MsT@133120 |
//     lutV@165888 | traj@690176  (total 1214464 B; guarded).

#define TT 512
#define BB 512
#define HH 128
#define NSs 64
#define NMm 34
#define NBb 128

typedef unsigned short u16;
typedef float f2 __attribute__((ext_vector_type(2)));

// ---- precompute M tables (f64 accumulate, f32 store; + transposed copies)
__global__ __launch_bounds__(256) void precompute_M(
    const float* __restrict__ embed,
    const float* __restrict__ Wm, const float* __restrict__ bm,
    const float* __restrict__ Wb, const float* __restrict__ bb,
    const float* __restrict__ Ws, const float* __restrict__ bs,
    float* __restrict__ Mm32, float* __restrict__ Ms32,
    float* __restrict__ Mb32, float* __restrict__ MmT,
    float* __restrict__ MsT) {
  __shared__ double e[HH];
  const int v = blockIdx.x;
  const int tid = threadIdx.x;  // 256
  if (tid < HH) e[tid] = (double)embed[v * HH + tid];
  __syncthreads();
  if (tid < NMm) {
    const int j = tid;
    double acc = 0.0;
    for (int h = 0; h < HH; ++h) acc += e[h] * (double)Wm[h * NMm + j];
    const float r = (float)(acc + (double)bm[j]);
    Mm32[v * NMm + j] = r;
    MmT[j * 128 + v] = r;
  } else if (tid < NMm + NSs) {
    const int j = tid - NMm;
    double acc = 0.0;
    for (int h = 0; h < HH; ++h) acc += e[h] * (double)Ws[h * NSs + j];
    const float r = (float)(acc + (double)bs[j]);
    Ms32[v * NSs + j] = r;
    MsT[j * 128 + v] = r;
  } else if (tid < NMm + NSs + NBb) {
    const int j = tid - NMm - NSs;
    double acc = 0.0;
    for (int h = 0; h < HH; ++h) acc += e[h] * (double)Wb[h * NBb + j];
    Mb32[v * NBb + j] = (float)(acc + (double)bb[j]);
  }
}

// ---- build decision LUT: block = (s,r) pair, thread = v. Coalesced reads
// from transposed tables; arithmetic bit-identical to r12-r18. Layout:
// lutV[v*2048 + s*32 + r] (u16).
__global__ __launch_bounds__(128) void build_lut(
    const float* __restrict__ Wm, const float* __restrict__ Ws,
    const float* __restrict__ MmT, const float* __restrict__ MsT,
    u16* __restrict__ lutV) {
  __shared__ float wms[NMm], wmr[NMm], wss[NSs], wsr[NSs];  // 784 B
  const int s = blockIdx.x >> 5;    // 0..63
  const int r = blockIdx.x & 31;    // 0..31
  const int tid = threadIdx.x;      // 128 = one v per thread
  if (tid < NMm) {
    wms[tid] = Wm[(128 + s) * NMm + tid];
    wmr[tid] = Wm[(192 + r) * NMm + tid];
  }
  if (tid < NSs) {
    wss[tid] = Ws[(128 + s) * NSs + tid];
    wsr[tid] = Ws[(192 + r) * NSs + tid];
  }
  __syncthreads();

  const int v = tid;
  int bestm = INT_MIN, act = 0;
#pragma unroll
  for (int j = 0; j < NMm; ++j) {
    const double val = (double)MmT[j * 128 + v] + (double)wms[j] + (double)wmr[j];
    const int iv = (int)(val * 67108864.0);
    if (iv > bestm) { bestm = iv; act = j; }
  }
  int bests = INT_MIN, ns = 0;
#pragma unroll
  for (int j = 0; j < NSs; ++j) {
    const double val = (double)MsT[j * 128 + v] + (double)wss[j] + (double)wsr[j];
    const int iv = (int)(val * 67108864.0);
    if (iv > bests) { bests = iv; ns = j; }
  }
  lutV[(unsigned)v * 2048 + (unsigned)blockIdx.x] = (u16)(act | (ns << 6));
}

// one 4KB slice -> 4x uint4 per lane (16 u32): chunk c = words [c*256,(c+1)*256),
// lane l in chunk c holds words c*256 + 4l .. +3 (dwordx4).
__device__ __forceinline__ void load_slice(uint4* Wk, const char* lutB,
                                           unsigned v, int lane) {
  const uint4* src = (const uint4*)(lutB + ((size_t)(v & 127u) << 12));
  Wk[0] = src[lane];
  Wk[1] = src[64 + lane];
  Wk[2] = src[128 + lane];
  Wk[3] = src[192 + lane];
}

// ---- phase 1: trajectory via register-resident LUT slices.
// 128 blocks x 256 threads (4 chains/block, 1 chain/wave). Unroll-4 groups;
// slice buffer W4[k] consumed at position k, reloaded 3 positions earlier.
__global__ __launch_bounds__(256) void sm_phase1(
    const int* __restrict__ x, const int* __restrict__ tact,
    const int* __restrict__ tstate, const int* __restrict__ forc,
    const u16* __restrict__ lutV, u16* __restrict__ traj) {
  __shared__ uint4 sPk4[4][TT / 4];  // 8192 B, packed inputs as uint4 groups
  unsigned* sPk = (unsigned*)sPk4;
  const int tid = threadIdx.x;
  const int base = blockIdx.x * 4;
  for (int i = tid; i < 4 * TT; i += 256) {
    const int w = i >> 9, t = i & (TT - 1);
    const int g = t * BB + base + w;
    sPk[w * TT + t] = (unsigned)x[g] | ((unsigned)tact[g] << 8) |
                      ((unsigned)tstate[g] << 16) | ((unsigned)forc[g] << 24);
  }
  __syncthreads();

  const int lane = tid & 63;
  const int w = tid >> 6;
  const int b = base + w;
  const char* lutB = (const char*)lutV;

  uint4 W4[4][4];
  uint4 cur4 = sPk4[w][0];
  uint4 next4 = sPk4[w][1];
  load_slice(W4[0], lutB, cur4.x, lane);
  load_slice(W4[1], lutB, cur4.y, lane);
  load_slice(W4[2], lutB, cur4.z, lane);
  load_slice(W4[3], lutB, cur4.w, lane);

  int stackv = 0;  // lane i holds stack[i]
  int ptr = 0, rr = 0, s = 0;
  int myv = 0;     // lane-rotated traj capture

  for (int g = 0; g < TT / 4; ++g) {
#pragma unroll
    for (int k = 0; k < 4; ++k) {
      const int t = g * 4 + k;
      const unsigned pk =
          (k == 0) ? cur4.x : (k == 1) ? cur4.y : (k == 2) ? cur4.z : cur4.w;
      const unsigned pk_s = __builtin_amdgcn_readfirstlane(pk);

      // off-chain: traj capture + slice prefetch (writes the buffer consumed
      // 3 positions later; WAR-clean — old value consumed 1 position ago)
      if (lane == (t & 63)) myv = s | (rr << 8);
      if (k == 0)      load_slice(W4[3], lutB, cur4.w, lane);
      else if (k == 1) load_slice(W4[0], lutB, next4.x, lane);
      else if (k == 2) load_slice(W4[1], lutB, next4.y, lane);
      else             load_slice(W4[2], lutB, next4.z, lane);

      int act, ns;
      if (pk_s >> 24) {  // forced (scalar path)
        act = (int)((pk_s >> 8) & 63u);
        ns = (int)((pk_s >> 16) & 63u);
      } else {
        const int idx = s * 32 + rr;      // scalar
        const int Wi = idx >> 1;          // u32 word index in slice
        const int c = (Wi >> 8) & 3;      // chunk
        const uint4 P = (c & 1) ? W4[k][1] : W4[k][0];
        const uint4 Q = (c & 1) ? W4[k][3] : W4[k][2];
        const uint4 R = (c & 2) ? Q : P;
        const int j = Wi & 3;
        const unsigned e0 = (j & 1) ? R.y : R.x;
        const unsigned e1 = (j & 1) ? R.w : R.z;
        const unsigned g2 = (j & 2) ? e1 : e0;
        const int lsel = (Wi >> 2) & 63;
        const unsigned word = (unsigned)__builtin_amdgcn_readlane((int)g2, lsel);
        const unsigned val = (idx & 1) ? (word >> 16) : (word & 0xffffu);
        act = (int)(val & 63u);
        ns = (int)((val >> 6) & 63u);
      }

      const bool ispush = act >= 2;
      int npn = ptr + (ispush ? 1 : 0) - (act == 1 ? 1 : 0);
      npn = npn < 0 ? 0 : (npn > 63 ? 63 : npn);
      if (ispush && lane == npn) stackv = act - 2;
      rr = __builtin_amdgcn_readlane(stackv, npn);
      ptr = npn;
      s = ns;

      if ((t & 63) == 63)  // off-chain scatter store, [t][b] layout
        traj[((t & ~63) + lane) * BB + b] = (u16)myv;
    }
    cur4 = next4;
    const int gn = (g + 2 < TT / 4) ? g + 2 : TT / 4 - 1;
    next4 = sPk4[w][gn];
  }
}

// ---- phase 2: materialize all logits. 4096 blocks x 256t = 16384 waves,
// 16 contiguous rows/wave; traj[t][b] -> 32B contiguous scalar reads.
__global__ __launch_bounds__(256) void sm_phase2(
    const int* __restrict__ x, const u16* __restrict__ traj,
    const float* __restrict__ Wm, const float* __restrict__ Wb,
    const float* __restrict__ Ws,
    const float* __restrict__ Mm32, const float* __restrict__ Ms32,
    const float* __restrict__ Mb32, float* __restrict__ out) {
  const int tid = threadIdx.x;
  const int lane = tid & 63;
  const int wid = blockIdx.x * 4 + (tid >> 6);   // 16384 waves
  float* outLM = out;                                  // [T,B,34]
  float* outLB = out + (size_t)TT * BB * NMm;          // [T,B,128]
  float* outLS = out + (size_t)TT * BB * (NMm + NBb);  // [T,B,64]

  const int row0 = wid * 16;
#pragma unroll 2
  for (int k = 0; k < 16; ++k) {
    const int row = row0 + k;
    const int xv = x[row];            // wave-uniform -> scalar load
    const int pr = traj[row];         // [t][b] == flat row  (contiguous)
    const int s = pr & 255;
    const int r = pr >> 8;
    const int rs = 128 + s, rr = 192 + r;
    if (lane < NMm)
      outLM[(size_t)row * NMm + lane] =
          Mm32[xv * NMm + lane] + Wm[rs * NMm + lane] + Wm[rr * NMm + lane];
    outLS[(size_t)row * NSs + lane] =
        Ms32[xv * NSs + lane] + Ws[rs * NSs + lane] + Ws[rr * NSs + lane];
    const f2 mb  = *(const f2*)&Mb32[xv * NBb + 2 * lane];
    const f2 wbs = *(const f2*)&Wb[rs * NBb + 2 * lane];
    const f2 wbr = *(const f2*)&Wb[rr * NBb + 2 * lane];
    f2 o;
    o.x = mb.x + wbs.x + wbr.x;   // same per-element add order as r14-r18
    o.y = mb.y + wbs.y + wbr.y;
    *(f2*)&outLB[(size_t)row * NBb + 2 * lane] = o;
  }
}

extern "C" void kernel_launch(void* const* d_in, const int* in_sizes, int n_in,
                              void* d_out, int out_size, void* d_ws, size_t ws_size,
                              hipStream_t stream) {
  if (ws_size < 1214464) return;  // signature: absmax 0.3457 -> ws too small

  const int* x     = (const int*)d_in[0];
  const int* tactp = (const int*)d_in[1];
  const int* tstp  = (const int*)d_in[2];
  const int* forcp = (const int*)d_in[3];
  const float* embed = (const float*)d_in[4];
  const float* Wm = (const float*)d_in[5];
  const float* bm = (const float*)d_in[6];
  const float* Wb = (const float*)d_in[7];
  const float* bb = (const float*)d_in[8];
  const float* Ws = (const float*)d_in[9];
  const float* bs = (const float*)d_in[10];

  char* wsp = (char*)d_ws;
  float* Mm32 = (float*)(wsp);            //  17408 B
  float* Ms32 = (float*)(wsp + 17408);    //  32768 B
  float* Mb32 = (float*)(wsp + 50176);    //  65536 B
  float* MmT  = (float*)(wsp + 115712);   //  17408 B
  float* MsT  = (float*)(wsp + 133120);   //  32768 B
  u16*   lutV = (u16*)(wsp + 165888);     // 524288 B
  u16*   traj = (u16*)(wsp + 690176);     // 524288 B -> total 1214464 B

  precompute_M<<<128, 256, 0, stream>>>(embed, Wm, bm, Wb, bb, Ws, bs,
                                        Mm32, Ms32, Mb32, MmT, MsT);
  build_lut<<<2048, 128, 0, stream>>>(Wm, Ws, MmT, MsT, lutV);
  sm_phase1<<<128, 256, 0, stream>>>(x, tactp, tstp, forcp, lutV, traj);
  sm_phase2<<<4096, 256, 0, stream>>>(x, traj, Wm, Wb, Ws,
                                      Mm32, Ms32, Mb32, (float*)d_out);
}

// Round 20
// 323.426 us; speedup vs baseline: 1.3050x; 1.3050x over previous
//
#include <hip/hip_runtime.h>
#include <stdint.h>
#include <limits.h>

// StackMachineCell — fused producer/consumer design (round 20).
// r19 post-mortem: register-slice W4[4][4] escaped via pointer -> scratch
// (VGPR 36, 11MB scratch writes, 422us). Reverted chain to r17 (best: e2e
// 192, ~560cy/step). New lever: FUSE phase2 under phase1's latency-bound
// chain. 128 blocks x 512 threads: waves 0-3 = producer chains (r17 loop,
// bit-identical), waves 4-7 = consumers spinning on per-chain LDS progress
// counters, materializing rows with phase2's exact math. Phase2's ~50us and
// the global traj stores vanish; producers and consumers share SIMDs (chain
// is stalled ~80%, consumers use idle issue slots).
// Sync: single-writer volatile LDS counter, fence every 8 steps, producers
// never wait on consumers -> deadlock-free, deterministic.
// ws: Mm32@0 | Ms32@17408 | Mb32@50176 | MmT@115712 | MsT@133120 |
//     lut@165888  (total 690176 B; guarded).

#define TT 512
#define BB 512
#define HH 128
#define NSs 64
#define NMm 34
#define NBb 128

typedef unsigned short u16;
typedef float f2 __attribute__((ext_vector_type(2)));

// ---- precompute M tables (f64 accumulate, f32 store; + transposed copies)
__global__ __launch_bounds__(256) void precompute_M(
    const float* __restrict__ embed,
    const float* __restrict__ Wm, const float* __restrict__ bm,
    const float* __restrict__ Wb, const float* __restrict__ bb,
    const float* __restrict__ Ws, const float* __restrict__ bs,
    float* __restrict__ Mm32, float* __restrict__ Ms32,
    float* __restrict__ Mb32, float* __restrict__ MmT,
    float* __restrict__ MsT) {
  __shared__ double e[HH];
  const int v = blockIdx.x;
  const int tid = threadIdx.x;  // 256
  if (tid < HH) e[tid] = (double)embed[v * HH + tid];
  __syncthreads();
  if (tid < NMm) {
    const int j = tid;
    double acc = 0.0;
    for (int h = 0; h < HH; ++h) acc += e[h] * (double)Wm[h * NMm + j];
    const float r = (float)(acc + (double)bm[j]);
    Mm32[v * NMm + j] = r;
    MmT[j * 128 + v] = r;
  } else if (tid < NMm + NSs) {
    const int j = tid - NMm;
    double acc = 0.0;
    for (int h = 0; h < HH; ++h) acc += e[h] * (double)Ws[h * NSs + j];
    const float r = (float)(acc + (double)bs[j]);
    Ms32[v * NSs + j] = r;
    MsT[j * 128 + v] = r;
  } else if (tid < NMm + NSs + NBb) {
    const int j = tid - NMm - NSs;
    double acc = 0.0;
    for (int h = 0; h < HH; ++h) acc += e[h] * (double)Wb[h * NBb + j];
    Mb32[v * NBb + j] = (float)(acc + (double)bb[j]);
  }
}

// ---- build decision LUT: block = (s,r) pair, thread = v. Coalesced reads
// from transposed tables; arithmetic bit-identical to r12-r19. Layout
// lut[(s*32+r)*128 + v] (r17's — the passing 192us config).
__global__ __launch_bounds__(128) void build_lut(
    const float* __restrict__ Wm, const float* __restrict__ Ws,
    const float* __restrict__ MmT, const float* __restrict__ MsT,
    u16* __restrict__ lut) {
  __shared__ float wms[NMm], wmr[NMm], wss[NSs], wsr[NSs];  // 784 B
  const int s = blockIdx.x >> 5;    // 0..63
  const int r = blockIdx.x & 31;    // 0..31
  const int tid = threadIdx.x;      // 128 = one v per thread
  if (tid < NMm) {
    wms[tid] = Wm[(128 + s) * NMm + tid];
    wmr[tid] = Wm[(192 + r) * NMm + tid];
  }
  if (tid < NSs) {
    wss[tid] = Ws[(128 + s) * NSs + tid];
    wsr[tid] = Ws[(192 + r) * NSs + tid];
  }
  __syncthreads();

  const int v = tid;
  int bestm = INT_MIN, act = 0;
#pragma unroll
  for (int j = 0; j < NMm; ++j) {
    const double val = (double)MmT[j * 128 + v] + (double)wms[j] + (double)wmr[j];
    const int iv = (int)(val * 67108864.0);
    if (iv > bestm) { bestm = iv; act = j; }
  }
  int bests = INT_MIN, ns = 0;
#pragma unroll
  for (int j = 0; j < NSs; ++j) {
    const double val = (double)MsT[j * 128 + v] + (double)wss[j] + (double)wsr[j];
    const int iv = (int)(val * 67108864.0);
    if (iv > bests) { bests = iv; ns = j; }
  }
  lut[(unsigned)blockIdx.x * 128 + v] = (u16)(act | (ns << 6));
}

// ---- fused: 128 blocks x 512 threads. Waves 0-3 produce trajectories
// (r17 chain, bit-identical); waves 4-7 consume and write all logits
// (phase2 math, bit-identical). Block-local LDS handoff.
__global__ __launch_bounds__(512) void sm_fused(
    const int* __restrict__ x, const int* __restrict__ tact,
    const int* __restrict__ tstate, const int* __restrict__ forc,
    const u16* __restrict__ lut,
    const float* __restrict__ Wm, const float* __restrict__ Wb,
    const float* __restrict__ Ws,
    const float* __restrict__ Mm32, const float* __restrict__ Ms32,
    const float* __restrict__ Mb32, float* __restrict__ out) {
  __shared__ unsigned sPk[4][TT];              // 8192 B
  __shared__ volatile u16 trajL[4][TT];        // 4096 B
  __shared__ volatile unsigned cnt[4];         //   16 B
  const int tid = threadIdx.x;
  const int base = blockIdx.x * 4;
  if (tid < 4) cnt[tid] = 0;
  for (int i = tid; i < 4 * TT; i += 512) {
    const int c = i >> 9, t = i & (TT - 1);
    const int g = t * BB + base + c;
    sPk[c][t] = (unsigned)x[g] | ((unsigned)tact[g] << 8) |
                ((unsigned)tstate[g] << 16) | ((unsigned)forc[g] << 24);
  }
  __syncthreads();  // last barrier; roles diverge below

  const int lane = tid & 63;
  const int w = tid >> 6;

  if (w < 4) {
    // ================= producer: r17 chain, verbatim semantics ==========
    const int c = w;
    int stackv = 0;  // lane i holds stack[i]
    int ptr = 0, rr = 0, s = 0;
    unsigned p0 = sPk[c][0], p1 = sPk[c][1], p2 = sPk[c][2];

    for (int t = 0; t < TT; ++t) {
      const unsigned p3 = sPk[c][t + 3 < TT ? t + 3 : TT - 1];
      const unsigned pk_s = __builtin_amdgcn_readfirstlane(p0);

      if (lane == 0) trajL[c][t] = (u16)(s | (rr << 8));  // carry-in (s,r)

      int act, ns;
      if (pk_s >> 24) {  // forced: extract from VGPR p0
        act = (int)((p0 >> 8) & 63u);
        ns = (int)((p0 >> 16) & 63u);
      } else {
        const int idx = s * 4096 + rr * 128 + (int)(p0 & 127u);  // VGPR math
        const int lv = lut[idx];  // vector load, L2-hot
        act = lv & 63;
        ns = (lv >> 6) & 63;
      }

      const bool ispush = act >= 2;
      int npn = ptr + (ispush ? 1 : 0) - (act == 1 ? 1 : 0);
      npn = npn < 0 ? 0 : (npn > 63 ? 63 : npn);
      if (ispush && lane == npn) stackv = act - 2;
      rr = __builtin_amdgcn_ds_bpermute(npn * 4, stackv);
      ptr = npn;
      s = ns;

      if ((t & 7) == 7) {  // publish progress (single writer, monotonic)
        __threadfence_block();
        if (lane == 0) cnt[c] = (unsigned)(t + 1);
      }
      p0 = p1; p1 = p2; p2 = p3;
    }
  } else {
    // ================= consumer: phase2 math, verbatim ==================
    const int c = w - 4;
    const int b = base + c;
    float* outLM = out;                                  // [T,B,34]
    float* outLB = out + (size_t)TT * BB * NMm;          // [T,B,128]
    float* outLS = out + (size_t)TT * BB * (NMm + NBb);  // [T,B,64]

    for (int t = 0; t < TT; ++t) {
      while (cnt[c] <= (unsigned)t) __builtin_amdgcn_s_sleep(1);
      const unsigned pk = sPk[c][t];
      const int xv = (int)(pk & 127u);
      const int pr = trajL[c][t];
      const int s = pr & 255;
      const int r = pr >> 8;
      const int rs = 128 + s, rr = 192 + r;
      const int row = t * BB + b;
      if (lane < NMm)
        outLM[(size_t)row * NMm + lane] =
            Mm32[xv * NMm + lane] + Wm[rs * NMm + lane] + Wm[rr * NMm + lane];
      outLS[(size_t)row * NSs + lane] =
          Ms32[xv * NSs + lane] + Ws[rs * NSs + lane] + Ws[rr * NSs + lane];
      const f2 mb  = *(const f2*)&Mb32[xv * NBb + 2 * lane];
      const f2 wbs = *(const f2*)&Wb[rs * NBb + 2 * lane];
      const f2 wbr = *(const f2*)&Wb[rr * NBb + 2 * lane];
      f2 o;
      o.x = mb.x + wbs.x + wbr.x;   // same per-element add order as r14-r19
      o.y = mb.y + wbs.y + wbr.y;
      *(f2*)&outLB[(size_t)row * NBb + 2 * lane] = o;
    }
  }
}

extern "C" void kernel_launch(void* const* d_in, const int* in_sizes, int n_in,
                              void* d_out, int out_size, void* d_ws, size_t ws_size,
                              hipStream_t stream) {
  if (ws_size < 690176) return;  // signature: absmax 0.3457 -> ws too small

  const int* x     = (const int*)d_in[0];
  const int* tactp = (const int*)d_in[1];
  const int* tstp  = (const int*)d_in[2];
  const int* forcp = (const int*)d_in[3];
  const float* embed = (const float*)d_in[4];
  const float* Wm = (const float*)d_in[5];
  const float* bm = (const float*)d_in[6];
  const float* Wb = (const float*)d_in[7];
  const float* bb = (const float*)d_in[8];
  const float* Ws = (const float*)d_in[9];
  const float* bs = (const float*)d_in[10];

  char* wsp = (char*)d_ws;
  float* Mm32 = (float*)(wsp);            //  17408 B
  float* Ms32 = (float*)(wsp + 17408);    //  32768 B
  float* Mb32 = (float*)(wsp + 50176);    //  65536 B
  float* MmT  = (float*)(wsp + 115712);   //  17408 B
  float* MsT  = (float*)(wsp + 133120);   //  32768 B
  u16*   lut  = (u16*)(wsp + 165888);     // 524288 B -> total 690176 B

  precompute_M<<<128, 256, 0, stream>>>(embed, Wm, bm, Wb, bb, Ws, bs,
                                        Mm32, Ms32, Mb32, MmT, MsT);
  build_lut<<<2048, 128, 0, stream>>>(Wm, Ws, MmT, MsT, lut);
  sm_fused<<<128, 512, 0, stream>>>(x, tactp, tstp, forcp, lut,
                                    Wm, Wb, Ws, Mm32, Ms32, Mb32,
                                    (float*)d_out);
}

// Round 21
// 322.065 us; speedup vs baseline: 1.3105x; 1.0042x over previous
//
#include <hip/hip_runtime.h>
#include <stdint.h>
#include <limits.h>

// StackMachineCell — fused producer/consumer design (round 21).
// r20 post-mortem: bare __launch_bounds__(512) register-capped sm_fused to
// 16 VGPR (r10/r11 pathology) -> all chain+consumer state spilled to scratch
// (FETCH 20MB, 300us). r13 proved (512,1) compiles the same block width to
// 88 VGPR, no spill. Single change this round: __launch_bounds__(512, 1).
// Design recap: 128 blocks x 512t; waves 0-3 = producer chains (r17 loop,
// bit-identical trajectory), waves 4-7 = consumers spinning on per-chain
// LDS progress counters, writing all logits (phase2 math, bit-identical).
// Producers never wait on consumers -> deadlock-free, deterministic.
// ws: Mm32@0 | Ms32@17408 | Mb32@50176 | MmT@115712 | MsT@133120 |
//     lut@165888  (total 690176 B; guarded).

#define TT 512
#define BB 512
#define HH 128
#define NSs 64
#define NMm 34
#define NBb 128

typedef unsigned short u16;
typedef float f2 __attribute__((ext_vector_type(2)));

// ---- precompute M tables (f64 accumulate, f32 store; + transposed copies)
__global__ __launch_bounds__(256) void precompute_M(
    const float* __restrict__ embed,
    const float* __restrict__ Wm, const float* __restrict__ bm,
    const float* __restrict__ Wb, const float* __restrict__ bb,
    const float* __restrict__ Ws, const float* __restrict__ bs,
    float* __restrict__ Mm32, float* __restrict__ Ms32,
    float* __restrict__ Mb32, float* __restrict__ MmT,
    float* __restrict__ MsT) {
  __shared__ double e[HH];
  const int v = blockIdx.x;
  const int tid = threadIdx.x;  // 256
  if (tid < HH) e[tid] = (double)embed[v * HH + tid];
  __syncthreads();
  if (tid < NMm) {
    const int j = tid;
    double acc = 0.0;
    for (int h = 0; h < HH; ++h) acc += e[h] * (double)Wm[h * NMm + j];
    const float r = (float)(acc + (double)bm[j]);
    Mm32[v * NMm + j] = r;
    MmT[j * 128 + v] = r;
  } else if (tid < NMm + NSs) {
    const int j = tid - NMm;
    double acc = 0.0;
    for (int h = 0; h < HH; ++h) acc += e[h] * (double)Ws[h * NSs + j];
    const float r = (float)(acc + (double)bs[j]);
    Ms32[v * NSs + j] = r;
    MsT[j * 128 + v] = r;
  } else if (tid < NMm + NSs + NBb) {
    const int j = tid - NMm - NSs;
    double acc = 0.0;
    for (int h = 0; h < HH; ++h) acc += e[h] * (double)Wb[h * NBb + j];
    Mb32[v * NBb + j] = (float)(acc + (double)bb[j]);
  }
}

// ---- build decision LUT: block = (s,r) pair, thread = v. Coalesced reads
// from transposed tables; arithmetic bit-identical to r12-r20. Layout
// lut[(s*32+r)*128 + v].
__global__ __launch_bounds__(128) void build_lut(
    const float* __restrict__ Wm, const float* __restrict__ Ws,
    const float* __restrict__ MmT, const float* __restrict__ MsT,
    u16* __restrict__ lut) {
  __shared__ float wms[NMm], wmr[NMm], wss[NSs], wsr[NSs];  // 784 B
  const int s = blockIdx.x >> 5;    // 0..63
  const int r = blockIdx.x & 31;    // 0..31
  const int tid = threadIdx.x;      // 128 = one v per thread
  if (tid < NMm) {
    wms[tid] = Wm[(128 + s) * NMm + tid];
    wmr[tid] = Wm[(192 + r) * NMm + tid];
  }
  if (tid < NSs) {
    wss[tid] = Ws[(128 + s) * NSs + tid];
    wsr[tid] = Ws[(192 + r) * NSs + tid];
  }
  __syncthreads();

  const int v = tid;
  int bestm = INT_MIN, act = 0;
#pragma unroll
  for (int j = 0; j < NMm; ++j) {
    const double val = (double)MmT[j * 128 + v] + (double)wms[j] + (double)wmr[j];
    const int iv = (int)(val * 67108864.0);
    if (iv > bestm) { bestm = iv; act = j; }
  }
  int bests = INT_MIN, ns = 0;
#pragma unroll
  for (int j = 0; j < NSs; ++j) {
    const double val = (double)MsT[j * 128 + v] + (double)wss[j] + (double)wsr[j];
    const int iv = (int)(val * 67108864.0);
    if (iv > bests) { bests = iv; ns = j; }
  }
  lut[(unsigned)blockIdx.x * 128 + v] = (u16)(act | (ns << 6));
}

// ---- fused: 128 blocks x 512 threads (min 1 wave/EU -> VGPR cap 256).
// Waves 0-3 produce trajectories (r17 chain); waves 4-7 consume and write
// all logits (phase2 math). Block-local LDS handoff.
__global__ __launch_bounds__(512, 1) void sm_fused(
    const int* __restrict__ x, const int* __restrict__ tact,
    const int* __restrict__ tstate, const int* __restrict__ forc,
    const u16* __restrict__ lut,
    const float* __restrict__ Wm, const float* __restrict__ Wb,
    const float* __restrict__ Ws,
    const float* __restrict__ Mm32, const float* __restrict__ Ms32,
    const float* __restrict__ Mb32, float* __restrict__ out) {
  __shared__ unsigned sPk[4][TT];              // 8192 B
  __shared__ volatile u16 trajL[4][TT];        // 4096 B
  __shared__ volatile unsigned cnt[4];         //   16 B
  const int tid = threadIdx.x;
  const int base = blockIdx.x * 4;
  if (tid < 4) cnt[tid] = 0;
  for (int i = tid; i < 4 * TT; i += 512) {
    const int c = i >> 9, t = i & (TT - 1);
    const int g = t * BB + base + c;
    sPk[c][t] = (unsigned)x[g] | ((unsigned)tact[g] << 8) |
                ((unsigned)tstate[g] << 16) | ((unsigned)forc[g] << 24);
  }
  __syncthreads();  // last barrier; roles diverge below

  const int lane = tid & 63;
  const int w = tid >> 6;

  if (w < 4) {
    // ================= producer: r17 chain, verbatim semantics ==========
    const int c = w;
    int stackv = 0;  // lane i holds stack[i]
    int ptr = 0, rr = 0, s = 0;
    unsigned p0 = sPk[c][0], p1 = sPk[c][1], p2 = sPk[c][2];

    for (int t = 0; t < TT; ++t) {
      const unsigned p3 = sPk[c][t + 3 < TT ? t + 3 : TT - 1];
      const unsigned pk_s = __builtin_amdgcn_readfirstlane(p0);

      if (lane == 0) trajL[c][t] = (u16)(s | (rr << 8));  // carry-in (s,r)

      int act, ns;
      if (pk_s >> 24) {  // forced: extract from VGPR p0
        act = (int)((p0 >> 8) & 63u);
        ns = (int)((p0 >> 16) & 63u);
      } else {
        const int idx = s * 4096 + rr * 128 + (int)(p0 & 127u);  // VGPR math
        const int lv = lut[idx];  // vector load, L2-hot
        act = lv & 63;
        ns = (lv >> 6) & 63;
      }

      const bool ispush = act >= 2;
      int npn = ptr + (ispush ? 1 : 0) - (act == 1 ? 1 : 0);
      npn = npn < 0 ? 0 : (npn > 63 ? 63 : npn);
      if (ispush && lane == npn) stackv = act - 2;
      rr = __builtin_amdgcn_ds_bpermute(npn * 4, stackv);
      ptr = npn;
      s = ns;

      if ((t & 7) == 7) {  // publish progress (single writer, monotonic)
        __threadfence_block();
        if (lane == 0) cnt[c] = (unsigned)(t + 1);
      }
      p0 = p1; p1 = p2; p2 = p3;
    }
  } else {
    // ================= consumer: phase2 math, verbatim ==================
    const int c = w - 4;
    const int b = base + c;
    float* outLM = out;                                  // [T,B,34]
    float* outLB = out + (size_t)TT * BB * NMm;          // [T,B,128]
    float* outLS = out + (size_t)TT * BB * (NMm + NBb);  // [T,B,64]

    for (int t = 0; t < TT; ++t) {
      while (cnt[c] <= (unsigned)t) __builtin_amdgcn_s_sleep(1);
      const unsigned pk = sPk[c][t];
      const int xv = (int)(pk & 127u);
      const int pr = trajL[c][t];
      const int s = pr & 255;
      const int r = pr >> 8;
      const int rs = 128 + s, rr = 192 + r;
      const int row = t * BB + b;
      if (lane < NMm)
        outLM[(size_t)row * NMm + lane] =
            Mm32[xv * NMm + lane] + Wm[rs * NMm + lane] + Wm[rr * NMm + lane];
      outLS[(size_t)row * NSs + lane] =
          Ms32[xv * NSs + lane] + Ws[rs * NSs + lane] + Ws[rr * NSs + lane];
      const f2 mb  = *(const f2*)&Mb32[xv * NBb + 2 * lane];
      const f2 wbs = *(const f2*)&Wb[rs * NBb + 2 * lane];
      const f2 wbr = *(const f2*)&Wb[rr * NBb + 2 * lane];
      f2 o;
      o.x = mb.x + wbs.x + wbr.x;   // same per-element add order as r14-r20
      o.y = mb.y + wbs.y + wbr.y;
      *(f2*)&outLB[(size_t)row * NBb + 2 * lane] = o;
    }
  }
}

extern "C" void kernel_launch(void* const* d_in, const int* in_sizes, int n_in,
                              void* d_out, int out_size, void* d_ws, size_t ws_size,
                              hipStream_t stream) {
  if (ws_size < 690176) return;  // signature: absmax 0.3457 -> ws too small

  const int* x     = (const int*)d_in[0];
  const int* tactp = (const int*)d_in[1];
  const int* tstp  = (const int*)d_in[2];
  const int* forcp = (const int*)d_in[3];
  const float* embed = (const float*)d_in[4];
  const float* Wm = (const float*)d_in[5];
  const float* bm = (const float*)d_in[6];
  const float* Wb = (const float*)d_in[7];
  const float* bb = (const float*)d_in[8];
  const float* Ws = (const float*)d_in[9];
  const float* bs = (const float*)d_in[10];

  char* wsp = (char*)d_ws;
  float* Mm32 = (float*)(wsp);            //  17408 B
  float* Ms32 = (float*)(wsp + 17408);    //  32768 B
  float* Mb32 = (float*)(wsp + 50176);    //  65536 B
  float* MmT  = (float*)(wsp + 115712);   //  17408 B
  float* MsT  = (float*)(wsp + 133120);   //  32768 B
  u16*   lut  = (u16*)(wsp + 165888);     // 524288 B -> total 690176 B

  precompute_M<<<128, 256, 0, stream>>>(embed, Wm, bm, Wb, bb, Ws, bs,
                                        Mm32, Ms32, Mb32, MmT, MsT);
  build_lut<<<2048, 128, 0, stream>>>(Wm, Ws, MmT, MsT, lut);
  sm_fused<<<128, 512, 0, stream>>>(x, tactp, tstp, forcp, lut,
                                    Wm, Wb, Ws, Mm32, Ms32, Mb32,
                                    (float*)d_out);
}

// Round 22
// 171.629 us; speedup vs baseline: 2.4591x; 1.8765x over previous
//
#include <hip/hip_runtime.h>
#include <stdint.h>
#include <limits.h>

// StackMachineCell — fused producer/consumer, rebalanced (round 22).
// r21 post-mortem: WRITE_SIZE == exact output bytes -> NO spill; VGPR=16 is
// just a small kernel. The 301us is the CONSUMER side: 1 consumer wave per
// chain walks 512 rows serially (~600cy/row ~ 300us). Fusion starved phase2
// of its TLP. Fix: 256 blocks x 512t = 2 producer chains (waves 0-1, r17
// chain verbatim) + 6 consumers (waves 2-7; 3 per chain, rows t mod 3).
// Consumer throughput/chain x3 -> hides under producer (~560cy/step).
// Handoff: single-writer monotonic LDS cnt, fence every 8 steps, producers
// never wait -> deadlock-free, deterministic.
// ws: Mm32@0 | Ms32@17408 | Mb32@50176 | MmT@115712 | MsT@133120 |
//     lut@165888  (total 690176 B; guarded).

#define TT 512
#define BB 512
#define HH 128
#define NSs 64
#define NMm 34
#define NBb 128

typedef unsigned short u16;
typedef float f2 __attribute__((ext_vector_type(2)));

// ---- precompute M tables (f64 accumulate, f32 store; + transposed copies)
__global__ __launch_bounds__(256) void precompute_M(
    const float* __restrict__ embed,
    const float* __restrict__ Wm, const float* __restrict__ bm,
    const float* __restrict__ Wb, const float* __restrict__ bb,
    const float* __restrict__ Ws, const float* __restrict__ bs,
    float* __restrict__ Mm32, float* __restrict__ Ms32,
    float* __restrict__ Mb32, float* __restrict__ MmT,
    float* __restrict__ MsT) {
  __shared__ double e[HH];
  const int v = blockIdx.x;
  const int tid = threadIdx.x;  // 256
  if (tid < HH) e[tid] = (double)embed[v * HH + tid];
  __syncthreads();
  if (tid < NMm) {
    const int j = tid;
    double acc = 0.0;
    for (int h = 0; h < HH; ++h) acc += e[h] * (double)Wm[h * NMm + j];
    const float r = (float)(acc + (double)bm[j]);
    Mm32[v * NMm + j] = r;
    MmT[j * 128 + v] = r;
  } else if (tid < NMm + NSs) {
    const int j = tid - NMm;
    double acc = 0.0;
    for (int h = 0; h < HH; ++h) acc += e[h] * (double)Ws[h * NSs + j];
    const float r = (float)(acc + (double)bs[j]);
    Ms32[v * NSs + j] = r;
    MsT[j * 128 + v] = r;
  } else if (tid < NMm + NSs + NBb) {
    const int j = tid - NMm - NSs;
    double acc = 0.0;
    for (int h = 0; h < HH; ++h) acc += e[h] * (double)Wb[h * NBb + j];
    Mb32[v * NBb + j] = (float)(acc + (double)bb[j]);
  }
}

// ---- build decision LUT: block = (s,r) pair, thread = v. Bit-identical
// arithmetic to r12-r21. Layout lut[(s*32+r)*128 + v].
__global__ __launch_bounds__(128) void build_lut(
    const float* __restrict__ Wm, const float* __restrict__ Ws,
    const float* __restrict__ MmT, const float* __restrict__ MsT,
    u16* __restrict__ lut) {
  __shared__ float wms[NMm], wmr[NMm], wss[NSs], wsr[NSs];  // 784 B
  const int s = blockIdx.x >> 5;    // 0..63
  const int r = blockIdx.x & 31;    // 0..31
  const int tid = threadIdx.x;      // 128 = one v per thread
  if (tid < NMm) {
    wms[tid] = Wm[(128 + s) * NMm + tid];
    wmr[tid] = Wm[(192 + r) * NMm + tid];
  }
  if (tid < NSs) {
    wss[tid] = Ws[(128 + s) * NSs + tid];
    wsr[tid] = Ws[(192 + r) * NSs + tid];
  }
  __syncthreads();

  const int v = tid;
  int bestm = INT_MIN, act = 0;
#pragma unroll
  for (int j = 0; j < NMm; ++j) {
    const double val = (double)MmT[j * 128 + v] + (double)wms[j] + (double)wmr[j];
    const int iv = (int)(val * 67108864.0);
    if (iv > bestm) { bestm = iv; act = j; }
  }
  int bests = INT_MIN, ns = 0;
#pragma unroll
  for (int j = 0; j < NSs; ++j) {
    const double val = (double)MsT[j * 128 + v] + (double)wss[j] + (double)wsr[j];
    const int iv = (int)(val * 67108864.0);
    if (iv > bests) { bests = iv; ns = j; }
  }
  lut[(unsigned)blockIdx.x * 128 + v] = (u16)(act | (ns << 6));
}

// ---- fused: 256 blocks x 512 threads. Waves 0-1 = producer chains
// (r17 loop, bit-identical trajectory); waves 2-7 = consumers (3 per
// chain, rows t mod 3), phase2 math verbatim. Block-local LDS handoff.
__global__ __launch_bounds__(512, 1) void sm_fused(
    const int* __restrict__ x, const int* __restrict__ tact,
    const int* __restrict__ tstate, const int* __restrict__ forc,
    const u16* __restrict__ lut,
    const float* __restrict__ Wm, const float* __restrict__ Wb,
    const float* __restrict__ Ws,
    const float* __restrict__ Mm32, const float* __restrict__ Ms32,
    const float* __restrict__ Mb32, float* __restrict__ out) {
  __shared__ unsigned sPk[2][TT];              // 4096 B
  __shared__ volatile u16 trajL[2][TT];        // 2048 B
  __shared__ volatile unsigned cnt[2];         //    8 B
  const int tid = threadIdx.x;
  const int base = blockIdx.x * 2;
  if (tid < 2) cnt[tid] = 0;
  for (int i = tid; i < 2 * TT; i += 512) {
    const int c = i >> 9, t = i & (TT - 1);
    const int g = t * BB + base + c;
    sPk[c][t] = (unsigned)x[g] | ((unsigned)tact[g] << 8) |
                ((unsigned)tstate[g] << 16) | ((unsigned)forc[g] << 24);
  }
  __syncthreads();  // last barrier; roles diverge below

  const int lane = tid & 63;
  const int w = tid >> 6;

  if (w < 2) {
    // ================= producer: r17 chain, verbatim semantics ==========
    const int c = w;
    int stackv = 0;  // lane i holds stack[i]
    int ptr = 0, rr = 0, s = 0;
    unsigned p0 = sPk[c][0], p1 = sPk[c][1], p2 = sPk[c][2];

    for (int t = 0; t < TT; ++t) {
      const unsigned p3 = sPk[c][t + 3 < TT ? t + 3 : TT - 1];
      const unsigned pk_s = __builtin_amdgcn_readfirstlane(p0);

      if (lane == 0) trajL[c][t] = (u16)(s | (rr << 8));  // carry-in (s,r)

      int act, ns;
      if (pk_s >> 24) {  // forced: extract from VGPR p0
        act = (int)((p0 >> 8) & 63u);
        ns = (int)((p0 >> 16) & 63u);
      } else {
        const int idx = s * 4096 + rr * 128 + (int)(p0 & 127u);  // VGPR math
        const int lv = lut[idx];  // vector load, L2-hot
        act = lv & 63;
        ns = (lv >> 6) & 63;
      }

      const bool ispush = act >= 2;
      int npn = ptr + (ispush ? 1 : 0) - (act == 1 ? 1 : 0);
      npn = npn < 0 ? 0 : (npn > 63 ? 63 : npn);
      if (ispush && lane == npn) stackv = act - 2;
      rr = __builtin_amdgcn_ds_bpermute(npn * 4, stackv);
      ptr = npn;
      s = ns;

      if ((t & 7) == 7) {  // publish progress (single writer, monotonic)
        __threadfence_block();
        if (lane == 0) cnt[c] = (unsigned)(t + 1);
      }
      p0 = p1; p1 = p2; p2 = p3;
    }
  } else {
    // ======= consumer: 3 waves per chain, rows t = j, j+3, ...; =========
    const int c = (w - 2) & 1;
    const int j = (w - 2) >> 1;   // 0,1,2
    const int b = base + c;
    float* outLM = out;                                  // [T,B,34]
    float* outLB = out + (size_t)TT * BB * NMm;          // [T,B,128]
    float* outLS = out + (size_t)TT * BB * (NMm + NBb);  // [T,B,64]

    for (int t = j; t < TT; t += 3) {
      while (cnt[c] <= (unsigned)t) __builtin_amdgcn_s_sleep(1);
      const unsigned pk = sPk[c][t];
      const int xv = (int)(pk & 127u);
      const int pr = trajL[c][t];
      const int s = pr & 255;
      const int r = pr >> 8;
      const int rs = 128 + s, rr = 192 + r;
      const int row = t * BB + b;
      if (lane < NMm)
        outLM[(size_t)row * NMm + lane] =
            Mm32[xv * NMm + lane] + Wm[rs * NMm + lane] + Wm[rr * NMm + lane];
      outLS[(size_t)row * NSs + lane] =
          Ms32[xv * NSs + lane] + Ws[rs * NSs + lane] + Ws[rr * NSs + lane];
      const f2 mb  = *(const f2*)&Mb32[xv * NBb + 2 * lane];
      const f2 wbs = *(const f2*)&Wb[rs * NBb + 2 * lane];
      const f2 wbr = *(const f2*)&Wb[rr * NBb + 2 * lane];
      f2 o;
      o.x = mb.x + wbs.x + wbr.x;   // same per-element add order as r14-r21
      o.y = mb.y + wbs.y + wbr.y;
      *(f2*)&outLB[(size_t)row * NBb + 2 * lane] = o;
    }
  }
}

extern "C" void kernel_launch(void* const* d_in, const int* in_sizes, int n_in,
                              void* d_out, int out_size, void* d_ws, size_t ws_size,
                              hipStream_t stream) {
  if (ws_size < 690176) return;  // signature: absmax 0.3457 -> ws too small

  const int* x     = (const int*)d_in[0];
  const int* tactp = (const int*)d_in[1];
  const int* tstp  = (const int*)d_in[2];
  const int* forcp = (const int*)d_in[3];
  const float* embed = (const float*)d_in[4];
  const float* Wm = (const float*)d_in[5];
  const float* bm = (const float*)d_in[6];
  const float* Wb = (const float*)d_in[7];
  const float* bb = (const float*)d_in[8];
  const float* Ws = (const float*)d_in[9];
  const float* bs = (const float*)d_in[10];

  char* wsp = (char*)d_ws;
  float* Mm32 = (float*)(wsp);            //  17408 B
  float* Ms32 = (float*)(wsp + 17408);    //  32768 B
  float* Mb32 = (float*)(wsp + 50176);    //  65536 B
  float* MmT  = (float*)(wsp + 115712);   //  17408 B
  float* MsT  = (float*)(wsp + 133120);   //  32768 B
  u16*   lut  = (u16*)(wsp + 165888);     // 524288 B -> total 690176 B

  precompute_M<<<128, 256, 0, stream>>>(embed, Wm, bm, Wb, bb, Ws, bs,
                                        Mm32, Ms32, Mb32, MmT, MsT);
  build_lut<<<2048, 128, 0, stream>>>(Wm, Ws, MmT, MsT, lut);
  sm_fused<<<256, 512, 0, stream>>>(x, tactp, tstp, forcp, lut,
                                    Wm, Wb, Ws, Mm32, Ms32, Mb32,
                                    (float*)d_out);
}